// Round 6
// baseline (409.099 us; speedup 1.0000x reference)
//
#include <hip/hip_runtime.h>

#define DI __device__ __forceinline__

typedef __attribute__((ext_vector_type(8))) short bf16x8;  // 8 bf16 bit-patterns
typedef __attribute__((ext_vector_type(4))) short s16x4;
typedef __attribute__((ext_vector_type(4))) float f32x4;
typedef __attribute__((ext_vector_type(2))) unsigned int u32x2;

DI short f2bs(float x){ unsigned u = __float_as_uint(x);
  return (short)((u + 0x7FFF + ((u >> 16) & 1)) >> 16); }          // RNE f32->bf16
DI float bs2f(short s){ return __uint_as_float(((unsigned)(unsigned short)s) << 16); }
DI unsigned pack2(float a, float b){
  return (unsigned)(unsigned short)f2bs(a) | ((unsigned)(unsigned short)f2bs(b) << 16);
}
DI f32x4 MFMA(bf16x8 a, bf16x8 b, f32x4 c){
  return __builtin_amdgcn_mfma_f32_16x16x32_bf16(a, b, c, 0, 0, 0);
}

// Problem constants
constexpr int NP   = 8192;
constexpr int NTOT = 16384;     // B*NP (reference flattens batch)
constexpr int M    = 4096;      // B*M_ROIS
constexpr int C    = 128;
constexpr int O    = 256;
constexpr int NS   = 32;
constexpr int H    = 4;
constexpr int KP   = 160;       // padded K: 0..127 feats, 128..130 gx, rest 0
constexpr int GFS  = 168;       // gf LDS row stride (shorts): 336B, 16B-aligned, 2-way banks
constexpr int VS   = 264;       // vst LDS row stride (shorts): 528B, 16B-aligned, 2-way banks
constexpr float BNS = 0.99999500003749969f;  // 1/sqrt(1+1e-5)

// ---------------- K0a: features (B,C,NP) f32 -> fT bf16 [B*NP][C] ----------------
__global__ __launch_bounds__(256) void k_transpose(const float* __restrict__ feat,
                                                   short* __restrict__ fT){
  __shared__ float tile[128][65];
  int blk = blockIdx.x;
  int b  = blk >> 7;
  int n0 = (blk & 127) << 6;
  int t = threadIdx.x;
  int nn = t & 63, c4 = t >> 6;
  const float* src = feat + (size_t)b * C * NP;
  for(int i = 0; i < 32; i++){
    int c = c4 * 32 + i;
    tile[c][nn] = src[(size_t)c * NP + n0 + nn];
  }
  __syncthreads();
  int c2 = t & 127, nb = t >> 7;
  for(int j = 0; j < 32; j++){
    int n = nb + j * 2;
    fT[((size_t)(b * NP + n0 + n)) * C + c2] = f2bs(tile[c2][n]);
  }
}

// ---------------- K0b: pack weights (bf16) ----------------
__global__ __launch_bounds__(256) void k_pack(
    const float* __restrict__ kw, const float* __restrict__ v1w,
    const float* __restrict__ v2w,
    const float* __restrict__ vcw, const float* __restrict__ qcw,
    const float* __restrict__ kcw, const float* __restrict__ qkcw,
    const float* __restrict__ cw1, const float* __restrict__ rw1,
    short* __restrict__ keyP, short* __restrict__ v1P,
    short* __restrict__ v2b,
    short* __restrict__ gw,            // 4 x O x O bf16 (vc,qc,kc,qkc)
    short* __restrict__ cw1b, short* __restrict__ rw1b)
{
  int i = blockIdx.x * 256 + threadIdx.x;
  if(i < O * KP){
    int o = i / KP, k = i % KP;
    float a = 0.0f, b = 0.0f;
    if(k < 128){ a = kw[o*131 + 3 + k]; b = v1w[o*131 + 3 + k]; }
    else if(k < 131){ a = kw[o*131 + (k - 128)]; b = v1w[o*131 + (k - 128)]; }
    keyP[i] = f2bs(a);
    v1P[i]  = f2bs(b);
  }
  if(i < O * O){
    v2b[i] = f2bs(v2w[i]);
    gw[0*O*O + i] = f2bs(vcw[i]);
    gw[1*O*O + i] = f2bs(qcw[i]);
    gw[2*O*O + i] = f2bs(kcw[i]);
    gw[3*O*O + i] = f2bs(qkcw[i]);
  }
  if(i < (O/2) * O){
    cw1b[i] = f2bs(cw1[i]);
    rw1b[i] = f2bs(rw1[i]);
  }
}

// ---------------- K1: ball query, 1 wave per query (exact f32) ----------------
__global__ __launch_bounds__(64) void k_ballq(const float* __restrict__ xyz,
                                              const float* __restrict__ nxyz,
                                              int* __restrict__ idxo,
                                              float* __restrict__ gxo){
#pragma clang fp contract(off)
  int m = blockIdx.x;
  int lane = threadIdx.x;
  float qx = nxyz[m*3+0], qy = nxyz[m*3+1], qz = nxyz[m*3+2];
  __shared__ int sel[NS];
  int cnt = 0;
  for(int base = 0; base < NTOT; base += 64){
    int p = base + lane;
    float dx = qx - xyz[p*3+0], dy = qy - xyz[p*3+1], dz = qz - xyz[p*3+2];
    float d2 = dx*dx + dy*dy;     // numpy order: (x^2+y^2)+z^2, no contraction
    d2 = d2 + dz*dz;
    bool pred = d2 < 2.56f;
    unsigned long long bal = __ballot(pred);
    if(pred){
      int pos = cnt + __popcll(bal & ((1ull << lane) - 1ull));
      if(pos < NS) sel[pos] = p;
    }
    cnt += __popcll(bal);
    if(cnt >= NS) break;          // wave-uniform
  }
  __syncthreads();
  if(lane < NS){
    int s = 0;
    if(cnt > 0) s = (lane < cnt) ? sel[lane] : sel[0];  // pad with first; empty -> 0
    idxo[m*NS + lane] = s;
    gxo[(m*NS+lane)*3+0] = xyz[s*3+0] - qx;
    gxo[(m*NS+lane)*3+1] = xyz[s*3+1] - qy;
    gxo[(m*NS+lane)*3+2] = xyz[s*3+2] - qz;
  }
}

// ---------------- K2: fused convs + means, 2 queries/block (N=64) ----------------
// Halves per-query L2 weight traffic; 3 barriers / 2 queries; direct reg->global
// stores for keyo/valo (rows accumulate 128B-contiguous segments -> L2 merges).
__global__ __launch_bounds__(256, 2) void k_conv(
    const short* __restrict__ fT,
    const short* __restrict__ keyP, const short* __restrict__ v1P,
    const short* __restrict__ v2b,
    const float* __restrict__ posw,
    const float* __restrict__ g1, const float* __restrict__ b1,
    const float* __restrict__ g2, const float* __restrict__ b2,
    const int* __restrict__ idxw, const float* __restrict__ gxw,
    short* __restrict__ keyo, short* __restrict__ valo,
    float* __restrict__ mPos, float* __restrict__ mKey, float* __restrict__ mPK,
    int q0)
{
  int lq2 = blockIdx.x, t = threadIdx.x;
  int w = t >> 6, l = t & 63;
  int col = l & 15, kq = l >> 4;
  int ro = w * 64;
  __shared__ __align__(16) short gf[64 * GFS];    // 21504 B  (2 queries x 32 nbr)
  __shared__ __align__(16) short vst[64 * VS];    // 33792 B
  __shared__ float gxs[64 * 4];                   // 1024 B
  __shared__ int  sel[64];                        // 256 B   total 56.6 KB -> 2 blocks/CU
  int qg0 = q0 + lq2 * 2;
  if(t < 64){
    int qi = t >> 5, n = t & 31;
    int gq = qg0 + qi;
    sel[t] = idxw[gq*NS + n];
    gxs[t*4+0] = gxw[(gq*NS+n)*3+0];
    gxs[t*4+1] = gxw[(gq*NS+n)*3+1];
    gxs[t*4+2] = gxw[(gq*NS+n)*3+2];
    gxs[t*4+3] = 0.0f;
  }
  __syncthreads();
  // gather features: wave w -> rows w*16..w*16+15; 64 lanes x 4B = 128 channels
  for(int i = 0; i < 16; i++){
    int n = w*16 + i;
    int p = sel[n];
    *(unsigned*)&gf[n*GFS + l*2] = *(const unsigned*)(fT + (size_t)p * C + l*2);
  }
  // gx channels 128..130 + zero pad to 159 (thread t: row t&63, k-slots w*8..w*8+7)
  {
    int n = t & 63, j0 = (t >> 6) * 8;
    for(int j = 0; j < 8; j++){
      int k = j0 + j;
      float v = (k < 3) ? gxs[n*4 + k] : 0.0f;
      gf[n*GFS + 128 + k] = f2bs(v);
    }
  }
  __syncthreads();

  f32x4 acc[4][4];
  const f32x4 vzero = {0.0f, 0.0f, 0.0f, 0.0f};

  // ---- v = relu(bn1(W_v1 @ gf)) -> vst ----
  for(int mt=0;mt<4;mt++) for(int nt=0;nt<4;nt++) acc[mt][nt] = vzero;
  for(int ks = 0; ks < 5; ks++){
    bf16x8 bf[4];
    for(int nt=0;nt<4;nt++)
      bf[nt] = *(const bf16x8*)&gf[(nt*16+col)*GFS + ks*32 + kq*8];
    for(int mt = 0; mt < 4; mt++){
      bf16x8 a = *(const bf16x8*)(v1P + (size_t)(ro + mt*16 + col)*KP + ks*32 + kq*8);
      for(int nt=0;nt<4;nt++) acc[mt][nt] = MFMA(a, bf[nt], acc[mt][nt]);
    }
  }
  for(int mt=0;mt<4;mt++){
    int o0 = ro + mt*16 + kq*4;
    float gg[4], bb[4];
    for(int r=0;r<4;r++){ gg[r] = g1[o0+r]; bb[r] = b1[o0+r]; }
    for(int nt=0;nt<4;nt++){
      s16x4 pk;
      for(int r=0;r<4;r++)
        pk[r] = f2bs(fmaxf(gg[r]*(acc[mt][nt][r] * BNS) + bb[r], 0.0f));
      *(s16x4*)&vst[(nt*16+col)*VS + o0] = pk;
    }
  }

  // ---- key = relu(W_key @ gf); direct stores + means ----
  for(int mt=0;mt<4;mt++) for(int nt=0;nt<4;nt++) acc[mt][nt] = vzero;
  for(int ks = 0; ks < 5; ks++){
    bf16x8 bf[4];
    for(int nt=0;nt<4;nt++)
      bf[nt] = *(const bf16x8*)&gf[(nt*16+col)*GFS + ks*32 + kq*8];
    for(int mt = 0; mt < 4; mt++){
      bf16x8 a = *(const bf16x8*)(keyP + (size_t)(ro + mt*16 + col)*KP + ks*32 + kq*8);
      for(int nt=0;nt<4;nt++) acc[mt][nt] = MFMA(a, bf[nt], acc[mt][nt]);
    }
  }
  for(int mt=0;mt<4;mt++){
    int o0 = ro + mt*16 + kq*4;
    float pw[4][3];
    for(int r=0;r<4;r++){ pw[r][0]=posw[(o0+r)*3+0]; pw[r][1]=posw[(o0+r)*3+1];
                          pw[r][2]=posw[(o0+r)*3+2]; }
    for(int qi=0; qi<2; qi++){
      float sp[4]={0,0,0,0}, sk[4]={0,0,0,0}, spk[4]={0,0,0,0};
      for(int h=0; h<2; h++){
        int nt = qi*2 + h;
        int n  = nt*16 + col;          // row in gxs (0..63)
        float gx0 = gxs[n*4+0], gx1 = gxs[n*4+1], gx2 = gxs[n*4+2];
        float kvv[4];
        for(int r=0;r<4;r++){
          float kk = fmaxf(acc[mt][nt][r], 0.0f);
          kvv[r] = kk;
          float pv = fmaxf(pw[r][0]*gx0 + pw[r][1]*gx1 + pw[r][2]*gx2, 0.0f);
          sp[r] += pv; sk[r] += kk; spk[r] += pv*kk;
        }
        // direct keyo store: 8B per lane, rows n of query qi
        int lql = lq2*2 + qi;
        int nn = h*16 + col;
        u32x2 pk2 = { pack2(kvv[0], kvv[1]), pack2(kvv[2], kvv[3]) };
        *(u32x2*)&keyo[((size_t)lql*NS + nn)*O + o0] = pk2;
      }
      // means reduce over 16 col lanes
      for(int r=0;r<4;r++){
        float a = sp[r], b = sk[r], c = spk[r];
        for(int msk=1; msk<16; msk<<=1){
          a += __shfl_xor(a, msk); b += __shfl_xor(b, msk); c += __shfl_xor(c, msk);
        }
        if(col == 0){
          int lql = lq2*2 + qi;
          mPos[(size_t)lql*O + o0 + r] = a * 0.03125f;
          mKey[(size_t)lql*O + o0 + r] = b * 0.03125f;
          mPK [(size_t)lql*O + o0 + r] = c * 0.03125f;
        }
      }
    }
  }
  __syncthreads();   // vst writes (from v-epilogue) visible to all

  // ---- val = relu(bn2(W_v2 @ v)), both queries in one pass ----
  for(int mt=0;mt<4;mt++) for(int nt=0;nt<4;nt++) acc[mt][nt] = vzero;
  for(int ks = 0; ks < 8; ks++){
    bf16x8 bf[4];
    for(int nt=0;nt<4;nt++)
      bf[nt] = *(const bf16x8*)&vst[(nt*16+col)*VS + ks*32 + kq*8];
    for(int mt = 0; mt < 4; mt++){
      bf16x8 a = *(const bf16x8*)(v2b + (size_t)(ro + mt*16 + col)*O + ks*32 + kq*8);
      for(int nt=0;nt<4;nt++) acc[mt][nt] = MFMA(a, bf[nt], acc[mt][nt]);
    }
  }
  for(int mt=0;mt<4;mt++){
    int o0 = ro + mt*16 + kq*4;
    float gg[4], bb[4];
    for(int r=0;r<4;r++){ gg[r] = g2[o0+r]; bb[r] = b2[o0+r]; }
    for(int nt=0;nt<4;nt++){
      float vv[4];
      for(int r=0;r<4;r++)
        vv[r] = fmaxf(gg[r]*(acc[mt][nt][r] * BNS) + bb[r], 0.0f);
      int lql = lq2*2 + (nt>>1);
      int nn  = (nt&1)*16 + col;
      u32x2 pk2 = { pack2(vv[0], vv[1]), pack2(vv[2], vv[3]) };
      *(u32x2*)&valo[((size_t)lql*NS + nn)*O + o0] = pk2;
    }
  }
}

// ---------------- K3: channel gates, batched MFMA (16 queries/block) ----------------
__global__ __launch_bounds__(256) void k_gates(
    const float* __restrict__ mPos, const float* __restrict__ mKey,
    const float* __restrict__ mPK, const short* __restrict__ gw,
    float* __restrict__ gates)
{
  int t = threadIdx.x, w = t >> 6, l = t & 63, col = l & 15, kq = l >> 4;
  int lq0 = blockIdx.x * 16;
  const float* A  = (w < 2) ? mPos : ((w == 2) ? mKey : mPK);
  const short* Wg = gw + (size_t)w * O * O;
  f32x4 acc[16];
  const f32x4 vzero = {0.0f,0.0f,0.0f,0.0f};
  for(int i=0;i<16;i++) acc[i] = vzero;
  for(int ks = 0; ks < 8; ks++){
    union { bf16x8 v; short e[8]; } u;
    const float* ap = A + (size_t)(lq0 + col)*O + ks*32 + kq*8;
    for(int j = 0; j < 8; j++) u.e[j] = f2bs(ap[j]);
    for(int nt = 0; nt < 16; nt++){
      bf16x8 bv = *(const bf16x8*)(Wg + (size_t)(nt*16 + col)*O + ks*32 + kq*8);
      acc[nt] = MFMA(u.v, bv, acc[nt]);
    }
  }
  for(int nt=0;nt<16;nt++) for(int r=0;r<4;r++){
    int lqq = lq0 + kq*4 + r;
    int oo = nt*16 + col;
    gates[((size_t)lqq*4 + w)*O + oo] = 1.0f / (1.0f + expf(-acc[nt][r]));
  }
}

// ---------------- K4: per-query attention + new_features (f32) ----------------
__global__ __launch_bounds__(256) void k_attn(
    const short* __restrict__ keyw, const short* __restrict__ valw,
    const float* __restrict__ gxw, const float* __restrict__ posw,
    const float* __restrict__ attw, const float* __restrict__ gates,
    float* __restrict__ outNF, int q0)
{
  int lq = blockIdx.x, q = q0 + lq, t = threadIdx.x;
  __shared__ float emL[O * 33];
  __shared__ float attnL[H * NS];
  __shared__ float gxs[NS * 3];
  __shared__ float partial[256];
  if(t < 96) gxs[t] = gxw[q*96 + t];
  float vc  = gates[((size_t)lq*4 + 0)*O + t];
  float qc  = gates[((size_t)lq*4 + 1)*O + t];
  float kc  = gates[((size_t)lq*4 + 2)*O + t];
  float qkc = gates[((size_t)lq*4 + 3)*O + t];
  float pw0 = posw[t*3+0], pw1 = posw[t*3+1], pw2 = posw[t*3+2];
  __syncthreads();
  float posr[NS];
  for(int n = 0; n < NS; n++)
    posr[n] = fmaxf(pw0*gxs[n*3] + pw1*gxs[n*3+1] + pw2*gxs[n*3+2], 0.0f);
  for(int n = 0; n < NS; n++){
    float k = bs2f(keyw[((size_t)lq*NS + n)*O + t]);
    emL[t*33 + n] = posr[n]*qc + k*kc + posr[n]*k*qkc;
  }
  __syncthreads();
  {
    int idx = t & 127, h = idx >> 5, n = idx & 31, half = t >> 7;
    float s = 0;
    const float* aw = attw + h*O + half*128;
    for(int o = 0; o < 128; o++) s += aw[o] * emL[(half*128 + o)*33 + n];
    partial[t] = s;
  }
  __syncthreads();
  if(t < 128){
    int h = t >> 5, n = t & 31;
    float s = partial[t] + partial[t + 128];
    float mx = s;
    for(int msk=1; msk<32; msk<<=1) mx = fmaxf(mx, __shfl_xor(mx, msk));
    float e = expf(s - mx);
    float sum = e;
    for(int msk=1; msk<32; msk<<=1) sum += __shfl_xor(sum, msk);
    attnL[h*NS + n] = e / sum;
  }
  __syncthreads();
  int h = t >> 6;
  float nf = 0;
  for(int n = 0; n < NS; n++){
    float v = bs2f(valw[((size_t)lq*NS + n)*O + t]);
    nf += (v + posr[n]*vc) * attnL[h*NS + n];
  }
  outNF[(size_t)q*O + t] = nf;
}

// ---------------- K5: cls/reg gating MLPs (64 queries/block) ----------------
__global__ __launch_bounds__(256) void k_fgate(
    const float* __restrict__ nf,            // = outNF (written by k_attn this launch)
    const short* __restrict__ cw1b, const float* __restrict__ cb1,
    const float* __restrict__ cw2, const float* __restrict__ cb2,
    const short* __restrict__ rw1b, const float* __restrict__ rb1,
    const float* __restrict__ rw2, const float* __restrict__ rb2,
    float* __restrict__ outC, float* __restrict__ outR)
{
  int t = threadIdx.x, w = t >> 6, l = t & 63, col = l & 15, kq = l >> 4;
  int q0 = blockIdx.x * 64;
  __shared__ float sC[64], sR[64];
  f32x4 acc[16];
  const f32x4 vzero = {0.0f,0.0f,0.0f,0.0f};
  for(int i=0;i<16;i++) acc[i] = vzero;
  int arow = q0 + w*16 + col;
  for(int ks = 0; ks < 8; ks++){
    union { bf16x8 v; short e[8]; } u;
    const float* ap = nf + (size_t)arow*O + ks*32 + kq*8;
    for(int j = 0; j < 8; j++) u.e[j] = f2bs(ap[j]);
    for(int nt = 0; nt < 16; nt++){
      const short* W1 = (nt < 8) ? cw1b : rw1b;
      int j = (nt & 7)*16 + col;
      bf16x8 bv = *(const bf16x8*)(W1 + (size_t)j*O + ks*32 + kq*8);
      acc[nt] = MFMA(u.v, bv, acc[nt]);
    }
  }
  for(int r = 0; r < 4; r++){
    float pc = 0, pr = 0;
    for(int nt = 0; nt < 8; nt++){
      int j = nt*16 + col;
      pc += fmaxf(acc[nt][r] + cb1[j], 0.0f) * cw2[j];
    }
    for(int nt = 8; nt < 16; nt++){
      int j = (nt - 8)*16 + col;
      pr += fmaxf(acc[nt][r] + rb1[j], 0.0f) * rw2[j];
    }
    for(int msk=1; msk<16; msk<<=1){ pc += __shfl_xor(pc, msk); pr += __shfl_xor(pr, msk); }
    if(col == 0){
      int qq = w*16 + kq*4 + r;
      sC[qq] = 1.0f / (1.0f + expf(-(pc + cb2[0])));
      sR[qq] = 1.0f / (1.0f + expf(-(pr + rb2[0])));
    }
  }
  __syncthreads();
  for(int qq = 0; qq < 64; qq++){
    float nv = nf[(size_t)(q0 + qq)*O + t];
    outC[(size_t)(q0 + qq)*O + t] = nv * sC[qq];
    outR[(size_t)(q0 + qq)*O + t] = nv * sR[qq];
  }
}

extern "C" void kernel_launch(void* const* d_in, const int* in_sizes, int n_in,
                              void* d_out, int out_size, void* d_ws, size_t ws_size,
                              hipStream_t stream)
{
  const float* xyz  = (const float*)d_in[0];
  const float* nxyz = (const float*)d_in[1];
  const float* feat = (const float*)d_in[2];
  const float* posw = (const float*)d_in[3];
  const float* keyw = (const float*)d_in[4];
  const float* v1w  = (const float*)d_in[5];
  const float* bn1g = (const float*)d_in[6];
  const float* bn1b = (const float*)d_in[7];
  const float* v2w  = (const float*)d_in[8];
  const float* bn2g = (const float*)d_in[9];
  const float* bn2b = (const float*)d_in[10];
  const float* attw = (const float*)d_in[11];
  const float* kcw  = (const float*)d_in[12];
  const float* qcw  = (const float*)d_in[13];
  const float* qkcw = (const float*)d_in[14];
  const float* vcw  = (const float*)d_in[15];
  const float* cw1  = (const float*)d_in[16];
  const float* cb1  = (const float*)d_in[17];
  const float* cw2  = (const float*)d_in[18];
  const float* cb2  = (const float*)d_in[19];
  const float* rw1  = (const float*)d_in[20];
  const float* rb1  = (const float*)d_in[21];
  const float* rw2  = (const float*)d_in[22];
  const float* rb2  = (const float*)d_in[23];

  // chunk size from ws_size (deterministic across calls; graph-safe)
  const size_t fixedB = 12000000;
  const size_t perQ   = 40960;
  int Q = 64;
  for(int cand : {4096, 2048, 1024, 512, 256, 128}){
    if(fixedB + (size_t)cand*perQ <= ws_size){ Q = cand; break; }
  }

  char* p = (char*)d_ws;
  auto alloc = [&](size_t bytes){ char* r = p; p += (bytes + 255) & ~size_t(255); return r; };
  short* fT    = (short*)alloc((size_t)NTOT*C*2);
  short* keyP  = (short*)alloc((size_t)O*KP*2);
  short* v1P   = (short*)alloc((size_t)O*KP*2);
  short* v2b   = (short*)alloc((size_t)O*O*2);
  short* gw    = (short*)alloc((size_t)4*O*O*2);
  short* cw1b  = (short*)alloc((size_t)(O/2)*O*2);
  short* rw1b  = (short*)alloc((size_t)(O/2)*O*2);
  int*   idxw  = (int*)  alloc((size_t)M*NS*4);
  float* gxw   = (float*)alloc((size_t)M*NS*3*4);
  short* keyo  = (short*)alloc((size_t)Q*NS*O*2);
  short* valo  = (short*)alloc((size_t)Q*NS*O*2);
  float* mPos  = (float*)alloc((size_t)Q*O*4);
  float* mKey  = (float*)alloc((size_t)Q*O*4);
  float* mPK   = (float*)alloc((size_t)Q*O*4);
  float* gates = (float*)alloc((size_t)Q*4*O*4);

  float* outNF = (float*)d_out;
  float* outC  = outNF + (size_t)M*O;
  float* outR  = outC  + (size_t)M*O;

  k_transpose<<<256, 256, 0, stream>>>(feat, fT);
  k_pack     <<<256, 256, 0, stream>>>(keyw, v1w, v2w, vcw, qcw, kcw, qkcw, cw1, rw1,
                                       keyP, v1P, v2b, gw, cw1b, rw1b);
  k_ballq    <<<M,   64,  0, stream>>>(xyz, nxyz, idxw, gxw);
  for(int q0 = 0; q0 < M; q0 += Q){
    k_conv  <<<Q/2,  256, 0, stream>>>(fT, keyP, v1P, v2b,
                                       posw, bn1g, bn1b, bn2g, bn2b,
                                       idxw, gxw, keyo, valo, mPos, mKey, mPK, q0);
    k_gates <<<Q/16, 256, 0, stream>>>(mPos, mKey, mPK, gw, gates);
    k_attn  <<<Q,    256, 0, stream>>>(keyo, valo, gxw, posw, attw, gates, outNF, q0);
  }
  k_fgate   <<<M/64, 256, 0, stream>>>(outNF, cw1b, cb1, cw2, cb2, rw1b, rb1, rw2, rb2, outC, outR);
}